// Round 6
// baseline (176.409 us; speedup 1.0000x reference)
//
#include <hip/hip_runtime.h>

// Shape-matching constraint projection, rot == Identity (the reference's
// SVD-derived rotation Vh^T @ Vh is identity up to SVD orthogonality noise;
// U and s are discarded).
//
//   com_c     = sum_p m*pred / sum_p m          (P=16 particles/constraint)
//   delta_pos = (V_w * (init - (pred - com))) / V_compliance
//   out[idx]  = V_predict[idx] + delta_pos ;  L_last passes through.
//
// R5 = R4 with the compile fix: __builtin_nontemporal_store needs a NATIVE
// vector type, not HIP_vector_type -> use ext_vector_type(4) float alias.
// R4 theory: R0-R3 (4 structures) all plateau at ~52us / 2.0 TB/s with
// minimal traffic (104MB HBM) and idle pipes -> test grid-stride software
// pipeline (prefetch next tile into registers while processing current),
// 1024 work blocks. Non-temporal stores for the write-once output. If this
// is ALSO ~52us, the cap is contention with harness restore/poison writeback
// during our dispatch -> effective roofline.

#define BLOCK 256

typedef float vf4 __attribute__((ext_vector_type(4)));

__device__ __forceinline__ void nt_store4(float4 v, float4* p) {
    vf4 x = {v.x, v.y, v.z, v.w};
    __builtin_nontemporal_store(x, reinterpret_cast<vf4*>(p));
}

struct Tile {
    int4   idx;
    float4 m, w, k;
    float4 pa, pb, pc;   // 4 predicted positions (packed float3 x4)
    float4 ia, ib, ic;   // 4 init positions
};

__device__ __forceinline__ void load_tile(
    const float* __restrict__ V_predict, const float* __restrict__ V_mass,
    const float* __restrict__ V_w,       const float* __restrict__ V_comp,
    const int*   __restrict__ C_shape,   const float* __restrict__ C_init,
    int t, Tile& T)
{
    T.idx = reinterpret_cast<const int4*>(C_shape)[t];
    T.m   = reinterpret_cast<const float4*>(V_mass)[t];
    T.w   = reinterpret_cast<const float4*>(V_w)[t];
    T.k   = reinterpret_cast<const float4*>(V_comp)[t];
    const float4* pp = reinterpret_cast<const float4*>(V_predict) + (size_t)t * 3;
    T.pa = pp[0]; T.pb = pp[1]; T.pc = pp[2];
    const float4* ip = reinterpret_cast<const float4*>(C_init) + (size_t)t * 3;
    T.ia = ip[0]; T.ib = ip[1]; T.ic = ip[2];
}

__device__ __forceinline__ void process_tile(
    const float* __restrict__ V_predict, const float* __restrict__ V_mass,
    const float* __restrict__ V_w,       const float* __restrict__ V_comp,
    float* __restrict__ out, int t, Tile T)
{
    const int gp0 = t << 2;
    const bool ok = (T.idx.x == gp0) & (T.idx.y == gp0 + 1) &
                    (T.idx.z == gp0 + 2) & (T.idx.w == gp0 + 3);

    if (!ok) {
        // general gather path (never taken for identity C_shape)
        const float3 q0 = *reinterpret_cast<const float3*>(V_predict + (size_t)T.idx.x * 3);
        const float3 q1 = *reinterpret_cast<const float3*>(V_predict + (size_t)T.idx.y * 3);
        const float3 q2 = *reinterpret_cast<const float3*>(V_predict + (size_t)T.idx.z * 3);
        const float3 q3 = *reinterpret_cast<const float3*>(V_predict + (size_t)T.idx.w * 3);
        T.pa = make_float4(q0.x, q0.y, q0.z, q1.x);
        T.pb = make_float4(q1.y, q1.z, q2.x, q2.y);
        T.pc = make_float4(q2.z, q3.x, q3.y, q3.z);
        T.m = make_float4(V_mass[T.idx.x], V_mass[T.idx.y], V_mass[T.idx.z], V_mass[T.idx.w]);
        T.w = make_float4(V_w[T.idx.x],    V_w[T.idx.y],    V_w[T.idx.z],    V_w[T.idx.w]);
        T.k = make_float4(V_comp[T.idx.x], V_comp[T.idx.y], V_comp[T.idx.z], V_comp[T.idx.w]);
    }

    const float p0x = T.pa.x, p0y = T.pa.y, p0z = T.pa.z;
    const float p1x = T.pa.w, p1y = T.pb.x, p1z = T.pb.y;
    const float p2x = T.pb.z, p2y = T.pb.w, p2z = T.pc.x;
    const float p3x = T.pc.y, p3y = T.pc.z, p3z = T.pc.w;

    float sx = T.m.x * p0x + T.m.y * p1x + T.m.z * p2x + T.m.w * p3x;
    float sy = T.m.x * p0y + T.m.y * p1y + T.m.z * p2y + T.m.w * p3y;
    float sz = T.m.x * p0z + T.m.y * p1z + T.m.z * p2z + T.m.w * p3z;
    float sm = T.m.x + T.m.y + T.m.z + T.m.w;

    // 2-step butterfly across the 4 threads of one constraint (16 particles).
    // 4-lane groups stay aligned under grid-stride (nthreads % 4 == 0).
    sx += __shfl_xor(sx, 1);
    sy += __shfl_xor(sy, 1);
    sz += __shfl_xor(sz, 1);
    sm += __shfl_xor(sm, 1);
    sx += __shfl_xor(sx, 2);
    sy += __shfl_xor(sy, 2);
    sz += __shfl_xor(sz, 2);
    sm += __shfl_xor(sm, 2);

    const float inv  = 1.0f / sm;
    const float comx = sx * inv;
    const float comy = sy * inv;
    const float comz = sz * inv;

    const float r0s = 1.0f / T.k.x, r1s = 1.0f / T.k.y,
                r2s = 1.0f / T.k.z, r3s = 1.0f / T.k.w;

    float4 oa, ob, oc;
    oa.x = p0x + (T.w.x * (T.ia.x - p0x + comx)) * r0s;
    oa.y = p0y + (T.w.x * (T.ia.y - p0y + comy)) * r0s;
    oa.z = p0z + (T.w.x * (T.ia.z - p0z + comz)) * r0s;
    oa.w = p1x + (T.w.y * (T.ia.w - p1x + comx)) * r1s;
    ob.x = p1y + (T.w.y * (T.ib.x - p1y + comy)) * r1s;
    ob.y = p1z + (T.w.y * (T.ib.y - p1z + comz)) * r1s;
    ob.z = p2x + (T.w.z * (T.ib.z - p2x + comx)) * r2s;
    ob.w = p2y + (T.w.z * (T.ib.w - p2y + comy)) * r2s;
    oc.x = p2z + (T.w.z * (T.ic.x - p2z + comz)) * r2s;
    oc.y = p3x + (T.w.w * (T.ic.y - p3x + comx)) * r3s;
    oc.z = p3y + (T.w.w * (T.ic.z - p3y + comy)) * r3s;
    oc.w = p3z + (T.w.w * (T.ic.w - p3z + comz)) * r3s;

    if (ok) {
        float4* op = reinterpret_cast<float4*>(out) + (size_t)t * 3;
        nt_store4(oa, op + 0);
        nt_store4(ob, op + 1);
        nt_store4(oc, op + 2);
    } else {
        float* o = out;
        o[(size_t)T.idx.x*3+0] = oa.x; o[(size_t)T.idx.x*3+1] = oa.y; o[(size_t)T.idx.x*3+2] = oa.z;
        o[(size_t)T.idx.y*3+0] = oa.w; o[(size_t)T.idx.y*3+1] = ob.x; o[(size_t)T.idx.y*3+2] = ob.y;
        o[(size_t)T.idx.z*3+0] = ob.z; o[(size_t)T.idx.z*3+1] = ob.w; o[(size_t)T.idx.z*3+2] = oc.x;
        o[(size_t)T.idx.w*3+0] = oc.y; o[(size_t)T.idx.w*3+1] = oc.z; o[(size_t)T.idx.w*3+2] = oc.w;
    }
}

__global__ __launch_bounds__(BLOCK) void shape_match_kernel(
    const float* __restrict__ V_predict,
    const float* __restrict__ L_last,
    const float* __restrict__ V_w,
    const float* __restrict__ V_mass,
    const int*   __restrict__ C_shape,
    const float* __restrict__ C_init,
    const float* __restrict__ V_comp,
    float*       __restrict__ out,
    float*       __restrict__ outL,
    int nquads, int work_blocks, int l_elems)
{
    if ((int)blockIdx.x >= work_blocks) {
        // ---- L_last passthrough (float4 copy) ----
        int i = (blockIdx.x - work_blocks) * blockDim.x + threadIdx.x;
        int n4 = l_elems >> 2;
        if (i < n4) {
            float4 v = reinterpret_cast<const float4*>(L_last)[i];
            nt_store4(v, reinterpret_cast<float4*>(outL) + i);
        }
        if (i == 0)
            for (int r = n4 << 2; r < l_elems; ++r) outL[r] = L_last[r];
        return;
    }

    const int nthreads = work_blocks * BLOCK;
    int t = blockIdx.x * BLOCK + threadIdx.x;
    if (t >= nquads) return;   // nthreads << nquads, never taken

    Tile cur, nxt;
    load_tile(V_predict, V_mass, V_w, V_comp, C_shape, C_init, t, cur);

    while (true) {
        const int tn = t + nthreads;
        const bool have_next = tn < nquads;   // uniform within 4-lane groups
        if (have_next)
            load_tile(V_predict, V_mass, V_w, V_comp, C_shape, C_init, tn, nxt);
        process_tile(V_predict, V_mass, V_w, V_comp, out, t, cur);
        if (!have_next) break;
        cur = nxt;
        t = tn;
    }
}

extern "C" void kernel_launch(void* const* d_in, const int* in_sizes, int n_in,
                              void* d_out, int out_size, void* d_ws, size_t ws_size,
                              hipStream_t stream)
{
    const float* V_predict = (const float*)d_in[0];
    const float* L_last    = (const float*)d_in[1];
    const float* V_w       = (const float*)d_in[2];
    const float* V_mass    = (const float*)d_in[3];
    const int*   C_shape   = (const int*)  d_in[4];
    const float* C_init    = (const float*)d_in[5];
    const float* V_comp    = (const float*)d_in[6];

    const int N     = in_sizes[0] / 3;   // vertices
    const int num_c = in_sizes[1];       // constraints (P fixed at 16)

    float* out  = (float*)d_out;
    float* outL = out + (size_t)N * 3;   // L_last output region

    const int nquads      = num_c * 4;                 // 4 particles/thread
    const int work_blocks = 1024;                      // grid-stride pipeline
    const int n4          = (num_c + 3) / 4;           // float4 copy count
    const int l_blocks    = (n4 + BLOCK - 1) / BLOCK;

    shape_match_kernel<<<work_blocks + l_blocks, BLOCK, 0, stream>>>(
        V_predict, L_last, V_w, V_mass, C_shape, C_init, V_comp,
        out, outL, nquads, work_blocks, num_c);
}

// Round 9
// 167.678 us; speedup vs baseline: 1.0521x; 1.0521x over previous
//
#include <hip/hip_runtime.h>

// Shape-matching constraint projection, rot == Identity (the reference's
// SVD-derived rotation Vh^T @ Vh is identity up to SVD orthogonality noise;
// U and s are discarded; no SVD needed).
//
//   com_c     = sum_p m*pred / sum_p m          (P=16 particles/constraint)
//   delta_pos = (V_w * (init - (pred - com))) / V_compliance
//   out[idx]  = V_predict[idx] + delta_pos ;  L_last passes through.
//
// R8 = R6/R7 resubmitted (two acquisition timeouts, no data). Measured-best
// structure (R0). Six structural variants (scalar, ILP-4, float4 streams,
// LDS transpose, grid-stride pipeline, NT stores) all pin TCC bytes /
// duration at 1.9-2.0 TB/s, with duration tracking byte count exactly ->
// the bench environment's memory system runs at ~2.0 TB/s for these
// isolated ~50us dispatches (DVFS: MCLK never ramps; the harness's own
// 147MB restore accounts for the rest of the headline at the same rate).
// Traffic is compulsory-only (102MB TCC-level vs 169MB logical; L2-resident
// restore data absorbs the difference). Lowest byte count + tied-best
// duration => roofline kernel.

#define P_PART 16

__global__ __launch_bounds__(256) void shape_match_kernel(
    const float* __restrict__ V_predict,
    const float* __restrict__ V_w,
    const float* __restrict__ V_mass,
    const int*   __restrict__ C_shape,
    const float* __restrict__ C_init,
    const float* __restrict__ V_comp,
    float*       __restrict__ out,
    int num_c)
{
    int t = blockIdx.x * blockDim.x + threadIdx.x;
    int c = t >> 4;          // constraint id
    if (c >= num_c) return;
    int gp = t;              // global particle slot = c*16 + p

    int idx = C_shape[gp];

    const float3 pred = *reinterpret_cast<const float3*>(V_predict + (size_t)idx * 3);
    const float3 init = *reinterpret_cast<const float3*>(C_init    + (size_t)gp  * 3);
    const float m    = V_mass[idx];
    const float w    = V_w[idx];
    const float comp = V_comp[idx];

    // weighted center of mass over the 16-lane group
    float sx = m * pred.x;
    float sy = m * pred.y;
    float sz = m * pred.z;
    float sm = m;
    #pragma unroll
    for (int off = 8; off >= 1; off >>= 1) {
        sx += __shfl_xor(sx, off, P_PART);
        sy += __shfl_xor(sy, off, P_PART);
        sz += __shfl_xor(sz, off, P_PART);
        sm += __shfl_xor(sm, off, P_PART);
    }
    const float inv = 1.0f / sm;
    const float comx = sx * inv;
    const float comy = sy * inv;
    const float comz = sz * inv;

    // delta_pos = w * (init - (pred - com)) * (1/comp)
    const float stiff = 1.0f / comp;
    float3 o;
    o.x = pred.x + w * (init.x - (pred.x - comx)) * stiff;
    o.y = pred.y + w * (init.y - (pred.y - comy)) * stiff;
    o.z = pred.z + w * (init.z - (pred.z - comz)) * stiff;

    *reinterpret_cast<float3*>(out + (size_t)idx * 3) = o;
}

extern "C" void kernel_launch(void* const* d_in, const int* in_sizes, int n_in,
                              void* d_out, int out_size, void* d_ws, size_t ws_size,
                              hipStream_t stream)
{
    const float* V_predict = (const float*)d_in[0];
    const float* L_last    = (const float*)d_in[1];
    const float* V_w       = (const float*)d_in[2];
    const float* V_mass    = (const float*)d_in[3];
    const int*   C_shape   = (const int*)  d_in[4];
    const float* C_init    = (const float*)d_in[5];
    const float* V_comp    = (const float*)d_in[6];

    const int N     = in_sizes[0] / 3;   // vertices
    const int num_c = in_sizes[1];       // constraints
    // P is fixed at 16 (shfl width assumption)

    float* out = (float*)d_out;

    const int total_particles = num_c * P_PART;
    const int block = 256;
    const int grid  = (total_particles + block - 1) / block;

    shape_match_kernel<<<grid, block, 0, stream>>>(
        V_predict, V_w, V_mass, C_shape, C_init, V_comp, out, num_c);

    // L_last passthrough -> second output, concatenated after V_predict_new
    hipMemcpyAsync(out + (size_t)N * 3, L_last, (size_t)num_c * sizeof(float),
                   hipMemcpyDeviceToDevice, stream);
}